// Round 5
// baseline (741.068 us; speedup 1.0000x reference)
//
#include <hip/hip_runtime.h>

#define S_LEN 2048
#define D_MODEL 4096
#define N_HEADS 32
#define N_KV 8
#define HEAD_DIM 128

typedef float f32x4 __attribute__((ext_vector_type(4)));
typedef short bf16x8 __attribute__((ext_vector_type(8)));

__device__ __forceinline__ unsigned short f2bf(float f) {
  unsigned int u = __float_as_uint(f);
  unsigned int r = (u + 0x7fffu + ((u >> 16) & 1u)) >> 16;
  return (unsigned short)r;
}
__device__ __forceinline__ float bf2f(unsigned short b) {
  return __uint_as_float(((unsigned int)b) << 16);
}
__device__ __forceinline__ void gload_lds16(const void* g, void* l) {
  __builtin_amdgcn_global_load_lds((const __attribute__((address_space(1))) void*)g,
                                   (__attribute__((address_space(3))) void*)l, 16, 0, 0);
}

// ---------------- f32 -> bf16 convert (vectorized, grid-stride) ----------------
__global__ void cvt_f32_bf16(const float* __restrict__ in, unsigned short* __restrict__ out, int n4) {
  int stride = gridDim.x * blockDim.x;
  for (int i = blockIdx.x * blockDim.x + threadIdx.x; i < n4; i += stride) {
    float4 v = ((const float4*)in)[i];
    unsigned int lo = (unsigned int)f2bf(v.x) | ((unsigned int)f2bf(v.y) << 16);
    unsigned int hi = (unsigned int)f2bf(v.z) | ((unsigned int)f2bf(v.w) << 16);
    uint2 o; o.x = lo; o.y = hi;
    ((uint2*)out)[i] = o;
  }
}

// ---------------- f32 K x N  ->  bf16 N x K (transpose + convert) ----------------
__global__ void transpose_cvt(const float* __restrict__ in, unsigned short* __restrict__ out,
                              int K, int N) {
  __shared__ float tile[32][33];
  int k0 = blockIdx.y << 5, n0 = blockIdx.x << 5;
  int tx = threadIdx.x, ty = threadIdx.y;
#pragma unroll
  for (int r = 0; r < 32; r += 8)
    tile[ty + r][tx] = in[(k0 + ty + r) * N + n0 + tx];
  __syncthreads();
#pragma unroll
  for (int r = 0; r < 32; r += 8)
    out[(n0 + ty + r) * K + k0 + tx] = f2bf(tile[tx][ty + r]);
}

// ---------------- bf16 transpose: out[c][r] = in[r][col0 + c] ----------------
__global__ void transpose_bf16(const unsigned short* __restrict__ in, unsigned short* __restrict__ out,
                               int inStride, int outStride, int col0) {
  __shared__ unsigned short tile[32][33];
  int r0 = blockIdx.y << 5, c0 = blockIdx.x << 5;
  int tx = threadIdx.x, ty = threadIdx.y;
#pragma unroll
  for (int r = 0; r < 32; r += 8)
    tile[ty + r][tx] = in[(r0 + ty + r) * inStride + col0 + c0 + tx];
  __syncthreads();
#pragma unroll
  for (int r = 0; r < 32; r += 8)
    out[(c0 + ty + r) * outStride + r0 + tx] = tile[tx][ty + r];
}

// ---------------- in-place RoPE on bf16 [S][rowStride], pairs (2p, 2p+1) per head ----------------
__global__ void rope_k(unsigned short* __restrict__ t, const float* __restrict__ cb,
                       const float* __restrict__ sb, int rowStride, int shift) {
  int idx = blockIdx.x * blockDim.x + threadIdx.x;
  int pos = idx >> shift;
  int wp = idx & ((1 << shift) - 1);
  int p = wp & 63;
  int col = ((wp >> 6) << 7) + (p << 1);
  unsigned int* addr = (unsigned int*)&t[pos * rowStride + col];
  unsigned int pr = *addr;
  float t0 = bf2f((unsigned short)(pr & 0xffffu));
  float t1 = bf2f((unsigned short)(pr >> 16));
  float c = cb[pos * 64 + p], s = sb[pos * 64 + p];
  float o0 = t0 * c - t1 * s;
  float o1 = t0 * s + t1 * c;
  *addr = (unsigned int)f2bf(o0) | ((unsigned int)f2bf(o1) << 16);
}

// ---------------- GEMM: C[M x N] = A[M x K] * Bt[N x K]^T   (bf16 in, f32 acc) ----------------
__device__ __forceinline__ void store_out(unsigned short* p, float v) { *p = f2bf(v); }
__device__ __forceinline__ void store_out(float* p, float v) { *p = v; }

template <typename OT>
__global__ __launch_bounds__(256, 2) void gemm_bt(const unsigned short* __restrict__ A,
                                                  const unsigned short* __restrict__ Bt,
                                                  OT* __restrict__ C, int M, int N, int K) {
  __shared__ __align__(16) unsigned short As[128 * 32];
  __shared__ __align__(16) unsigned short Bs[128 * 32];
  const int tid = threadIdx.x;
  const int w = tid >> 6, l = tid & 63;
  const int lrow = l & 15, lk = l >> 4;
  const int m0 = blockIdx.y * 128, n0 = blockIdx.x * 128;
  const int wm = (w >> 1) * 64, wn = (w & 1) * 64;
  f32x4 acc[4][4] = {};

  for (int kt = 0; kt < K; kt += 32) {
    __syncthreads();
#pragma unroll
    for (int p = 0; p < 2; ++p) {
      int e = (p * 256 + tid) * 8;
      int r = e >> 5, c = e & 31;
      gload_lds16(&A[(m0 + r) * K + kt + c], (char*)As + p * 4096 + w * 1024);
      gload_lds16(&Bt[(n0 + r) * K + kt + c], (char*)Bs + p * 4096 + w * 1024);
    }
    __syncthreads();
    bf16x8 af[4], bfr[4];
#pragma unroll
    for (int i = 0; i < 4; ++i)
      af[i] = *(const bf16x8*)&As[(wm + i * 16 + lrow) * 32 + lk * 8];
#pragma unroll
    for (int j = 0; j < 4; ++j)
      bfr[j] = *(const bf16x8*)&Bs[(wn + j * 16 + lrow) * 32 + lk * 8];
#pragma unroll
    for (int i = 0; i < 4; ++i)
#pragma unroll
      for (int j = 0; j < 4; ++j)
        acc[i][j] = __builtin_amdgcn_mfma_f32_16x16x32_bf16(af[i], bfr[j], acc[i][j], 0, 0, 0);
  }
#pragma unroll
  for (int i = 0; i < 4; ++i)
#pragma unroll
    for (int j = 0; j < 4; ++j)
#pragma unroll
      for (int r = 0; r < 4; ++r) {
        int row = m0 + wm + i * 16 + lk * 4 + r;
        int col = n0 + wn + j * 16 + lrow;
        store_out(&C[row * N + col], acc[i][j][r]);
      }
}

// ---------------- causal GQA flash attention (reg-staged pipeline) ----------------
// grid (16,32): block = (128 q-rows, head), 4 waves x 32 rows. KV tile 64.
// Per tile: [barrier][ds_write staged regs][issue t+1 global loads][barrier][compute].
// K/V LDS XOR-swizzled (source-side swizzle at load, read-side XOR on ds_read).
__global__ __launch_bounds__(256, 2) void attn_fwd(const unsigned short* __restrict__ Q,
                                                   const unsigned short* __restrict__ Kb,
                                                   const unsigned short* __restrict__ Vt,
                                                   unsigned short* __restrict__ Ctx) {
  __shared__ __align__(16) unsigned short Ks[64 * 128];   // [kv][hd], chunk^=(row&7)
  __shared__ __align__(16) unsigned short Vs[128 * 64];   // [hd][kv], chunk^=(row&7)
  __shared__ __align__(16) unsigned short Ps[4][32 * 72]; // per-wave P, pad 72

  const int tid = threadIdx.x, w = tid >> 6, l = tid & 63;
  const int lrow = l & 15, lk = l >> 4;
  const int qh = blockIdx.y;
  const int g = qh >> 2;                       // kv head
  const int qbi = gridDim.x - 1 - blockIdx.x;  // heavy (high-q) blocks first
  const int q0 = qbi * 128;
  const int wq0 = q0 + w * 32;
  const int tdiag = wq0 >> 6;                  // this wave's diagonal tile
  const float scale2 = 0.12751743f;            // log2(e)/sqrt(128)
  const int o_base = w * 1024 + (l << 4);

  // Q fragments in registers for the whole loop
  bf16x8 qf[2][4];
#pragma unroll
  for (int i = 0; i < 2; ++i)
#pragma unroll
    for (int ks = 0; ks < 4; ++ks)
      qf[i][ks] = *(const bf16x8*)&Q[(wq0 + i * 16 + lrow) * D_MODEL + qh * HEAD_DIM + ks * 32 + lk * 8];

  f32x4 o[2][8] = {};
  float mrun[2][4], lrun[2][4];
#pragma unroll
  for (int i = 0; i < 2; ++i)
#pragma unroll
    for (int r = 0; r < 4; ++r) { mrun[i][r] = -1e30f; lrun[i][r] = 0.0f; }

  uint4 kreg[4], vreg[4];
#define LOADT(tt)                                                                     \
  do {                                                                                \
    int kv0p = (tt) << 6;                                                             \
    _Pragma("unroll") for (int c = 0; c < 4; ++c) {                                   \
      int o_b = c * 4096 + o_base;                                                    \
      int rw = o_b >> 8;                                                              \
      int sck = ((o_b >> 4) & 15) ^ (rw & 7);                                         \
      kreg[c] = *(const uint4*)&Kb[(kv0p + rw) * 2048 + g * HEAD_DIM + sck * 8];      \
      int rv = o_b >> 7;                                                              \
      int scv = ((o_b >> 4) & 7) ^ (rv & 7);                                          \
      vreg[c] = *(const uint4*)&Vt[(g * HEAD_DIM + rv) * 2048 + kv0p + scv * 8];      \
    }                                                                                 \
  } while (0)

  LOADT(0);
  const int nt = (q0 + 128) >> 6;
  for (int t = 0; t < nt; ++t) {
    __syncthreads();  // all waves done reading previous tile
    // stage tile t from regs (linear LDS, data pre-swizzled at source)
#pragma unroll
    for (int c = 0; c < 4; ++c) {
      int o_b = c * 4096 + o_base;
      *(uint4*)((char*)Ks + o_b) = kreg[c];
      *(uint4*)((char*)Vs + o_b) = vreg[c];
    }
    if (t + 1 < nt) LOADT(t + 1);  // issue next-tile loads; latency hides under compute
    __syncthreads();
    if (t > tdiag) continue;       // fully masked for this wave; barriers still hit
    const int kv0 = t << 6;
    const bool dia = (t == tdiag);

    // S = Q K^T  (32 x 64)
    f32x4 sa[2][4] = {};
    __builtin_amdgcn_s_setprio(1);
#pragma unroll
    for (int ks = 0; ks < 4; ++ks) {
      bf16x8 kf[4];
#pragma unroll
      for (int j = 0; j < 4; ++j) {
        int row = j * 16 + lrow;
        kf[j] = *(const bf16x8*)&Ks[row * 128 + ((ks * 32 + lk * 8) ^ ((row & 7) << 3))];
      }
#pragma unroll
      for (int i = 0; i < 2; ++i)
#pragma unroll
        for (int j = 0; j < 4; ++j)
          sa[i][j] = __builtin_amdgcn_mfma_f32_16x16x32_bf16(qf[i][ks], kf[j], sa[i][j], 0, 0, 0);
    }
    __builtin_amdgcn_s_setprio(0);

    // scale (+ causal mask on diagonal tile only) into sa
    if (dia) {
#pragma unroll
      for (int i = 0; i < 2; ++i)
#pragma unroll
        for (int j = 0; j < 4; ++j) {
          int kvcol = kv0 + j * 16 + lrow;
#pragma unroll
          for (int r = 0; r < 4; ++r) {
            int qrow = wq0 + i * 16 + lk * 4 + r;
            float x = sa[i][j][r] * scale2;
            sa[i][j][r] = (kvcol > qrow) ? -1e30f : x;
          }
        }
    } else {
#pragma unroll
      for (int i = 0; i < 2; ++i)
#pragma unroll
        for (int j = 0; j < 4; ++j)
#pragma unroll
          for (int r = 0; r < 4; ++r) sa[i][j][r] *= scale2;
    }

    // row max (defer-max THR=8)
    float tmx[2][4];
    float grow = -1e30f;
#pragma unroll
    for (int i = 0; i < 2; ++i)
#pragma unroll
      for (int r = 0; r < 4; ++r) {
        float mx = fmaxf(fmaxf(sa[i][0][r], sa[i][1][r]), fmaxf(sa[i][2][r], sa[i][3][r]));
#pragma unroll
        for (int d = 1; d < 16; d <<= 1) mx = fmaxf(mx, __shfl_xor(mx, d));
        tmx[i][r] = mx;
        grow = fmaxf(grow, mx - mrun[i][r]);
      }
    if (__any(grow > 8.0f)) {
      float al[2][4];
#pragma unroll
      for (int i = 0; i < 2; ++i)
#pragma unroll
        for (int r = 0; r < 4; ++r) {
          float mnew = fmaxf(mrun[i][r], tmx[i][r]);
          float a = __builtin_exp2f(mrun[i][r] - mnew);
          mrun[i][r] = mnew;
          lrun[i][r] *= a;
          al[i][r] = a;
        }
#pragma unroll
      for (int i = 0; i < 2; ++i)
#pragma unroll
        for (int n = 0; n < 8; ++n)
#pragma unroll
          for (int r = 0; r < 4; ++r) o[i][n][r] *= al[i][r];
    }

    // P = exp2(sa - mrun), row-sum, stash to wave-local LDS
#pragma unroll
    for (int i = 0; i < 2; ++i)
#pragma unroll
      for (int r = 0; r < 4; ++r) {
        float ps[4];
        float rs = 0.0f;
#pragma unroll
        for (int j = 0; j < 4; ++j) { ps[j] = __builtin_exp2f(sa[i][j][r] - mrun[i][r]); rs += ps[j]; }
#pragma unroll
        for (int d = 1; d < 16; d <<= 1) rs += __shfl_xor(rs, d);
        lrun[i][r] += rs;
#pragma unroll
        for (int j = 0; j < 4; ++j)
          Ps[w][(i * 16 + lk * 4 + r) * 72 + j * 16 + lrow] = f2bf(ps[j]);
      }

    // O += P V
    __builtin_amdgcn_s_setprio(1);
#pragma unroll
    for (int ks = 0; ks < 2; ++ks) {
      bf16x8 pa[2];
#pragma unroll
      for (int i = 0; i < 2; ++i)
        pa[i] = *(const bf16x8*)&Ps[w][(i * 16 + lrow) * 72 + ks * 32 + lk * 8];
#pragma unroll
      for (int n = 0; n < 8; ++n) {
        int row = n * 16 + lrow;
        bf16x8 vf = *(const bf16x8*)&Vs[row * 64 + ((ks * 32 + lk * 8) ^ ((row & 7) << 3))];
#pragma unroll
        for (int i = 0; i < 2; ++i)
          o[i][n] = __builtin_amdgcn_mfma_f32_16x16x32_bf16(pa[i], vf, o[i][n], 0, 0, 0);
      }
    }
    __builtin_amdgcn_s_setprio(0);
  }
#undef LOADT

  // epilogue: O / l  -> ctx (bf16)
#pragma unroll
  for (int i = 0; i < 2; ++i) {
    float inv[4];
#pragma unroll
    for (int r = 0; r < 4; ++r) inv[r] = 1.0f / lrun[i][r];
#pragma unroll
    for (int n = 0; n < 8; ++n)
#pragma unroll
      for (int r = 0; r < 4; ++r) {
        int row = wq0 + i * 16 + lk * 4 + r;
        int col = n * 16 + lrow;
        Ctx[row * D_MODEL + qh * HEAD_DIM + col] = f2bf(o[i][n][r] * inv[r]);
      }
  }
}

// ---------------- host launch ----------------
extern "C" void kernel_launch(void* const* d_in, const int* in_sizes, int n_in,
                              void* d_out, int out_size, void* d_ws, size_t ws_size,
                              hipStream_t stream) {
  const float* x = (const float*)d_in[0];
  const float* wq = (const float*)d_in[1];
  const float* wk = (const float*)d_in[2];
  const float* wv = (const float*)d_in[3];
  const float* wo = (const float*)d_in[4];
  const float* fcos = (const float*)d_in[5];
  const float* fsin = (const float*)d_in[6];
  float* out = (float*)d_out;

  char* ws = (char*)d_ws;
  unsigned short* xb = (unsigned short*)ws;                      // 16MB: x bf16; later ctx
  unsigned short* ctx = xb;
  unsigned short* wt = (unsigned short*)(ws + (size_t)16 * 1024 * 1024);   // 32MB weights^T
  unsigned short* qb = (unsigned short*)(ws + (size_t)48 * 1024 * 1024);   // 16MB Q
  unsigned short* kvb = (unsigned short*)(ws + (size_t)64 * 1024 * 1024);  // 8MB K|V [2048][2048]
  unsigned short* vtg = (unsigned short*)(ws + (size_t)72 * 1024 * 1024);  // 4MB V^T [1024][2048]

  // x -> bf16
  cvt_f32_bf16<<<2048, 256, 0, stream>>>(x, xb, S_LEN * D_MODEL / 4);

  // Q = x @ wq
  transpose_cvt<<<dim3(128, 128), dim3(32, 8), 0, stream>>>(wq, wt, 4096, 4096);
  gemm_bt<unsigned short><<<dim3(32, 16), 256, 0, stream>>>(xb, wt, qb, S_LEN, 4096, 4096);

  // K|V = x @ [wk|wv]  (fused, N=2048)
  transpose_cvt<<<dim3(32, 128), dim3(32, 8), 0, stream>>>(wk, wt, 4096, 1024);
  transpose_cvt<<<dim3(32, 128), dim3(32, 8), 0, stream>>>(wv, wt + (size_t)1024 * 4096, 4096, 1024);
  gemm_bt<unsigned short><<<dim3(16, 16), 256, 0, stream>>>(xb, wt, kvb, S_LEN, 2048, 4096);

  // RoPE in-place on Q and K
  rope_k<<<(S_LEN * 2048) / 256, 256, 0, stream>>>(qb, fcos, fsin, 4096, 11);
  rope_k<<<(S_LEN * 512) / 256, 256, 0, stream>>>(kvb, fcos, fsin, 2048, 9);

  // V^T in global: vtg[c][r] = kvb[r][1024 + c]
  transpose_bf16<<<dim3(32, 64), dim3(32, 8), 0, stream>>>(kvb, vtg, 2048, 2048, 1024);

  // attention
  attn_fwd<<<dim3(16, 32), 256, 0, stream>>>(qb, kvb, vtg, ctx);

  // out = ctx @ wo  (f32 output)
  transpose_cvt<<<dim3(128, 128), dim3(32, 8), 0, stream>>>(wo, wt, 4096, 4096);
  gemm_bt<float><<<dim3(32, 16), 256, 0, stream>>>(ctx, wt, out, S_LEN, 4096, 4096);
}